// Round 4
// baseline (969.668 us; speedup 1.0000x reference)
//
#include <hip/hip_runtime.h>
#include <hip/hip_bf16.h>

#define BATCH   16
#define N_ANC   8649      // 31*31*9
#define SORT_N  16384     // padded pow2
#define PRE     6000
#define POST    1500
#define ROWW    188       // u32 words per mask row (6016 bits)
#define MROWS   6016      // rows incl. pad (16 pad rows in last group)
#define NGRP    188       // 188 groups of 32 rows
#define TI      256
#define TJ      256

// ---------------- Kernel 1: decode boxes + build sort keys ----------------
__global__ __launch_bounds__(256) void k_decode(
    const float* __restrict__ deltas, const float* __restrict__ probs,
    const float* __restrict__ anchors, float4* __restrict__ boxes,
    unsigned long long* __restrict__ keys)
{
    int t = blockIdx.x * 256 + threadIdx.x;
    if (t >= BATCH * SORT_N) return;
    int b = t / SORT_N;
    int n = t - b * SORT_N;
    if (n >= N_ANC) { keys[t] = ~0ULL; return; }

    float s = probs[(size_t)b * N_ANC + n];
    unsigned int bits = __float_as_uint(s);
    unsigned int u = bits ^ ((bits & 0x80000000u) ? 0xFFFFFFFFu : 0x80000000u);
    keys[(size_t)b * SORT_N + n] = ((unsigned long long)(~u) << 32) | (unsigned int)n;

    float4 a = ((const float4*)anchors)[n];
    float4 d = ((const float4*)deltas)[(size_t)b * N_ANC + n];
    float dy = d.x * 0.1f, dx = d.y * 0.1f, dh = d.z * 0.2f, dw = d.w * 0.2f;
    float ah = a.z - a.x, aw = a.w - a.y;
    float cy = a.x + 0.5f * ah, cx = a.y + 0.5f * aw;
    float bh = expf(dh) * ah, bw = expf(dw) * aw;
    float bcy = dy * ah + cy, bcx = dx * aw + cx;
    float y1 = bcy - 0.5f * bh, x1 = bcx - 0.5f * bw;
    boxes[(size_t)b * N_ANC + n] = make_float4(y1, x1, y1 + bh, x1 + bw);
}

// ---------------- Kernel 2: per-batch bitonic sort of 16384 keys ----------------
__global__ __launch_bounds__(1024) void k_sort(unsigned long long* __restrict__ keys)
{
    __shared__ unsigned long long sb[8192];   // 64 KB
    int b = blockIdx.x;
    unsigned long long* kb = keys + (size_t)b * SORT_N;

    for (int c = 0; c < 2; c++) {
        unsigned long long* g = kb + c * 8192;
        for (int t = threadIdx.x; t < 8192; t += 1024) sb[t] = g[t];
        __syncthreads();
        for (int k = 2; k <= 8192; k <<= 1) {
            for (int j = k >> 1; j >= 1; j >>= 1) {
                for (int p = threadIdx.x; p < 4096; p += 1024) {
                    int i  = ((p & ~(j - 1)) << 1) | (p & (j - 1));
                    int gi = (c << 13) | i;
                    bool asc = ((gi & k) == 0);
                    unsigned long long a = sb[i], b2 = sb[i | j];
                    bool sw = asc ? (a > b2) : (a < b2);
                    if (sw) { sb[i] = b2; sb[i | j] = a; }
                }
                __syncthreads();
            }
        }
        for (int t = threadIdx.x; t < 8192; t += 1024) g[t] = sb[t];
        __syncthreads();
    }

    for (int p = threadIdx.x; p < 8192; p += 1024) {
        unsigned long long a = kb[p], b2 = kb[p + 8192];
        if (a > b2) { kb[p] = b2; kb[p + 8192] = a; }
    }
    __syncthreads();

    for (int t = threadIdx.x; t < 8192; t += 1024) sb[t] = kb[t];
    __syncthreads();
    for (int j = 4096; j >= 1; j >>= 1) {
        for (int p = threadIdx.x; p < 4096; p += 1024) {
            int i = ((p & ~(j - 1)) << 1) | (p & (j - 1));
            unsigned long long a = sb[i], b2 = sb[i | j];
            if (a > b2) { sb[i] = b2; sb[i | j] = a; }
        }
        __syncthreads();
    }
    for (int t = threadIdx.x; t < 6016; t += 1024) kb[t] = sb[t];
}

// ---------------- Kernel 3: gather sorted boxes/scores ----------------
__global__ __launch_bounds__(256) void k_gather(
    const unsigned long long* __restrict__ keys, const float4* __restrict__ boxes,
    const float* __restrict__ probs,
    float4* __restrict__ sboxes, float* __restrict__ sscores)
{
    int t = blockIdx.x * 256 + threadIdx.x;
    if (t >= BATCH * PRE) return;
    int b = t / PRE;
    int r = t - b * PRE;
    unsigned long long k = keys[(size_t)b * SORT_N + r];
    int idx = (int)(k & 0xFFFFFFFFu);
    sboxes[(size_t)b * PRE + r]  = boxes[(size_t)b * N_ANC + idx];
    sscores[(size_t)b * PRE + r] = probs[(size_t)b * N_ANC + idx];
}

// ---------------- Kernel 4: IoU bit-matrix, 256x256 tiles, upper triangle ----------------
__global__ __launch_bounds__(256) void k_iou(
    const float4* __restrict__ sboxes, unsigned int* __restrict__ mask)
{
    int it = blockIdx.x;   // row tile 0..23
    int jt = blockIdx.y;   // col tile 0..23
    int b  = blockIdx.z;
    if (jt < it) return;   // lower-triangle tiles never consumed by scan

    __shared__ float4 jb[TJ];
    __shared__ float  ja[TJ];
    int t = threadIdx.x;
    int j = jt * TJ + t;
    float4 bj = (j < PRE) ? sboxes[(size_t)b * PRE + j]
                          : make_float4(-2e6f, -2e6f, -1.5e6f, -1.5e6f); // far dummy, area>0
    jb[t] = bj;
    ja[t] = (bj.z - bj.x) * (bj.w - bj.y);
    __syncthreads();

    int i = it * TI + t;
    if (i >= PRE) return;
    float4 bi = sboxes[(size_t)b * PRE + i];
    float areai = (bi.z - bi.x) * (bi.w - bi.y);

    unsigned int w[8];
    if (jt > it) {
        for (int wq = 0; wq < 8; wq++) {
            unsigned int bits = 0u;
            #pragma unroll
            for (int jj = 0; jj < 32; jj++) {
                int lj = wq * 32 + jj;
                float4 bx = jb[lj];
                float ih = fmaxf(fminf(bi.z, bx.z) - fmaxf(bi.x, bx.x), 0.0f);
                float iw = fmaxf(fminf(bi.w, bx.w) - fmaxf(bi.y, bx.y), 0.0f);
                float inter = ih * iw;
                float iou = inter / (areai + ja[lj] - inter + 1e-8f);
                if (iou > 0.7f) bits |= (1u << jj);
            }
            w[wq] = bits;
        }
    } else {
        for (int wq = 0; wq < 8; wq++) {
            int jbase = jt * TJ + wq * 32;
            unsigned int bits = 0u;
            if (jbase + 31 > i) {
                #pragma unroll
                for (int jj = 0; jj < 32; jj++) {
                    int lj = wq * 32 + jj;
                    float4 bx = jb[lj];
                    float ih = fmaxf(fminf(bi.z, bx.z) - fmaxf(bi.x, bx.x), 0.0f);
                    float iw = fmaxf(fminf(bi.w, bx.w) - fmaxf(bi.y, bx.y), 0.0f);
                    float inter = ih * iw;
                    float iou = inter / (areai + ja[lj] - inter + 1e-8f);
                    if (iou > 0.7f && (jbase + jj) > i) bits |= (1u << jj);
                }
            }
            w[wq] = bits;
        }
    }

    unsigned int* row = mask + ((size_t)b * MROWS + i) * ROWW + jt * 8;
    ((uint4*)row)[0] = make_uint4(w[0], w[1], w[2], w[3]);
    if (jt < 23) ((uint4*)row)[1] = make_uint4(w[4], w[5], w[6], w[7]);
}

// ---------------- Kernel 5: group-32 suppression scan (1 wave / batch) ----------------
// State distributed: lane l (l<47) owns words 4l..4l+3 (uint4 st).
// Per 32-row group: LDS-staged rows (double buffer, reg-staged prefetch),
// 32 statically-indexed tri registers, branchless serial resolve,
// OR of kept rows only. Critical path ~1/32 of the old per-row chain.
__global__ __launch_bounds__(64) void k_scan(
    const unsigned int* __restrict__ mask, int* __restrict__ out_idx,
    int* __restrict__ out_cnt)
{
    __shared__ unsigned int buf[2][NGRP ? 6016 : 1];  // 2 x 24064 B
    int b = blockIdx.x;
    int lane = threadIdx.x;
    const unsigned int* mb = mask + (size_t)b * MROWS * ROWW;
    bool lact = (lane < 47);

    uint4 st = make_uint4(0, 0, 0, 0);
    uint4 r[24];

    // prologue: stage group 0 into buf[0]
    {
        const uint4* src = (const uint4*)mb;
        #pragma unroll
        for (int t = 0; t < 23; t++) r[t] = src[t * 64 + lane];
        if (lane < 32) r[23] = src[23 * 64 + lane];
        uint4* dst = (uint4*)buf[0];
        #pragma unroll
        for (int t = 0; t < 23; t++) dst[t * 64 + lane] = r[t];
        if (lane < 32) dst[23 * 64 + lane] = r[23];
    }

    int cur = 0, cnt = 0;
    int* oi = out_idx + b * POST;

    for (int g = 0; g < NGRP; g++) {
        // 1. issue prefetch of group g+1 into regs (hides HBM latency under resolve)
        if (g + 1 < NGRP) {
            const uint4* src = (const uint4*)(mb + (size_t)(g + 1) * 32 * ROWW);
            #pragma unroll
            for (int t = 0; t < 23; t++) r[t] = src[t * 64 + lane];
            if (lane < 32) r[23] = src[23 * 64 + lane];
        }

        // 2. intra-group diagonal words (broadcast LDS reads, static registers)
        unsigned int tri[32];
        #pragma unroll
        for (int k = 0; k < 32; k++) tri[k] = buf[cur][k * ROWW + g];

        // 3. broadcast global suppress-word for this group
        unsigned int sw = (g & 2) ? ((g & 1) ? st.w : st.z)
                                  : ((g & 1) ? st.y : st.x);
        sw = __shfl(sw, g >> 2);

        // 4. branchless serial resolve (replicated across lanes)
        unsigned int valid = (g == NGRP - 1) ? 0xFFFFu : 0xFFFFFFFFu; // pad rows dead
        unsigned int alive = ~sw & valid;
        unsigned int keepm = 0;
        #pragma unroll
        for (int k = 0; k < 32; k++) {
            unsigned int bit = (alive >> k) & 1u;
            keepm |= bit << k;
            alive &= ~((0u - bit) & tri[k]);
        }

        // 5. cap truncation (exact reference semantics)
        int kc = __popc(keepm);
        if (cnt + kc > POST) {
            unsigned int km2 = keepm, trunc = 0u;
            int need = POST - cnt;
            for (int c = 0; c < need; c++) {
                int k = __ffs(km2) - 1;
                trunc |= 1u << k;
                km2 &= km2 - 1;
            }
            keepm = trunc;
            kc = need;
        }

        // 6. record kept indices
        if (lane == 0) {
            unsigned int km2 = keepm;
            int c = cnt;
            while (km2) {
                int k = __ffs(km2) - 1;
                km2 &= km2 - 1;
                oi[c++] = g * 32 + k;
            }
        }

        // 7. OR kept rows into distributed state (uniform branches)
        #pragma unroll
        for (int k = 0; k < 32; k++) {
            if (keepm & (1u << k)) {
                if (lact) {
                    uint4 v = *(const uint4*)&buf[cur][k * ROWW + 4 * lane];
                    st.x |= v.x; st.y |= v.y; st.z |= v.z; st.w |= v.w;
                }
            }
        }

        cnt += kc;
        if (cnt >= POST) break;

        // 8. commit prefetched regs to the other buffer
        if (g + 1 < NGRP) {
            uint4* dst = (uint4*)buf[cur ^ 1];
            #pragma unroll
            for (int t = 0; t < 23; t++) dst[t * 64 + lane] = r[t];
            if (lane < 32) dst[23 * 64 + lane] = r[23];
            cur ^= 1;
        }
    }
    if (lane == 0) out_cnt[b] = cnt;
}

// ---------------- Kernel 6: compact + clip output ----------------
__global__ __launch_bounds__(256) void k_out(
    const float4* __restrict__ sboxes, const float* __restrict__ sscores,
    const int* __restrict__ out_idx, const int* __restrict__ out_cnt,
    float* __restrict__ out)
{
    int t = blockIdx.x * 256 + threadIdx.x;
    if (t >= BATCH * POST) return;
    int b = t / POST;
    int r = t - b * POST;
    float4 v = make_float4(0, 0, 0, 0);
    float sc = 0.f;
    if (r < out_cnt[b]) {
        int i = out_idx[b * POST + r];
        float4 bx = sboxes[(size_t)b * PRE + i];
        v.x = fminf(fmaxf(bx.x, 0.f), 1.f);
        v.y = fminf(fmaxf(bx.y, 0.f), 1.f);
        v.z = fminf(fmaxf(bx.z, 0.f), 1.f);
        v.w = fminf(fmaxf(bx.w, 0.f), 1.f);
        sc = sscores[(size_t)b * PRE + i];
    }
    ((float4*)out)[t] = v;                  // roi_bboxes
    out[(size_t)BATCH * POST * 4 + t] = sc; // roi_scores
}

// ---------------- host ----------------
extern "C" void kernel_launch(void* const* d_in, const int* in_sizes, int n_in,
                              void* d_out, int out_size, void* d_ws, size_t ws_size,
                              hipStream_t stream)
{
    const float* deltas  = (const float*)d_in[0];
    const float* probs   = (const float*)d_in[1];
    const float* anchors = (const float*)d_in[2];
    float* out = (float*)d_out;

    char* ws = (char*)d_ws;
    size_t off = 0;
    auto alloc = [&](size_t bytes) {
        size_t o = off;
        off = (off + bytes + 255) & ~(size_t)255;
        return o;
    };
    float4* boxes            = (float4*)(ws + alloc((size_t)BATCH * N_ANC * 16));
    unsigned long long* keys = (unsigned long long*)(ws + alloc((size_t)BATCH * SORT_N * 8));
    float4* sboxes           = (float4*)(ws + alloc((size_t)BATCH * PRE * 16));
    float* sscores           = (float*)(ws + alloc((size_t)BATCH * PRE * 4));
    unsigned int* mask       = (unsigned int*)(ws + alloc((size_t)BATCH * MROWS * ROWW * 4));
    int* oidx                = (int*)(ws + alloc((size_t)BATCH * POST * 4));
    int* ocnt                = (int*)(ws + alloc((size_t)BATCH * 4));

    k_decode<<<(BATCH * SORT_N + 255) / 256, 256, 0, stream>>>(deltas, probs, anchors, boxes, keys);
    k_sort<<<BATCH, 1024, 0, stream>>>(keys);
    k_gather<<<(BATCH * PRE + 255) / 256, 256, 0, stream>>>(keys, boxes, probs, sboxes, sscores);
    k_iou<<<dim3(24, 24, BATCH), 256, 0, stream>>>(sboxes, mask);
    k_scan<<<BATCH, 64, 0, stream>>>(mask, oidx, ocnt);
    k_out<<<(BATCH * POST + 255) / 256, 256, 0, stream>>>(sboxes, sscores, oidx, ocnt, out);
}

// Round 5
// 710.764 us; speedup vs baseline: 1.3643x; 1.3643x over previous
//
#include <hip/hip_runtime.h>
#include <hip/hip_bf16.h>

#define BATCH   16
#define N_ANC   8649      // 31*31*9
#define SORT_N  16384     // padded pow2
#define PRE     6000
#define POST    1500
#define ROWW    188       // u32 words per mask row (6016 bits)
#define MROWS   6016      // rows incl. pad (16 pad rows in last group)
#define NGRP    188       // 188 groups of 32 rows
#define TI      256
#define TJ      256

// ---------------- Kernel 1: decode boxes + build sort keys ----------------
__global__ __launch_bounds__(256) void k_decode(
    const float* __restrict__ deltas, const float* __restrict__ probs,
    const float* __restrict__ anchors, float4* __restrict__ boxes,
    unsigned long long* __restrict__ keys)
{
    int t = blockIdx.x * 256 + threadIdx.x;
    if (t >= BATCH * SORT_N) return;
    int b = t / SORT_N;
    int n = t - b * SORT_N;
    if (n >= N_ANC) { keys[t] = ~0ULL; return; }

    float s = probs[(size_t)b * N_ANC + n];
    unsigned int bits = __float_as_uint(s);
    unsigned int u = bits ^ ((bits & 0x80000000u) ? 0xFFFFFFFFu : 0x80000000u);
    keys[(size_t)b * SORT_N + n] = ((unsigned long long)(~u) << 32) | (unsigned int)n;

    float4 a = ((const float4*)anchors)[n];
    float4 d = ((const float4*)deltas)[(size_t)b * N_ANC + n];
    float dy = d.x * 0.1f, dx = d.y * 0.1f, dh = d.z * 0.2f, dw = d.w * 0.2f;
    float ah = a.z - a.x, aw = a.w - a.y;
    float cy = a.x + 0.5f * ah, cx = a.y + 0.5f * aw;
    float bh = expf(dh) * ah, bw = expf(dw) * aw;
    float bcy = dy * ah + cy, bcx = dx * aw + cx;
    float y1 = bcy - 0.5f * bh, x1 = bcx - 0.5f * bw;
    boxes[(size_t)b * N_ANC + n] = make_float4(y1, x1, y1 + bh, x1 + bw);
}

// ---------------- Kernel 2: per-batch bitonic sort of 16384 keys ----------------
__global__ __launch_bounds__(1024) void k_sort(unsigned long long* __restrict__ keys)
{
    __shared__ unsigned long long sb[8192];   // 64 KB
    int b = blockIdx.x;
    unsigned long long* kb = keys + (size_t)b * SORT_N;

    for (int c = 0; c < 2; c++) {
        unsigned long long* g = kb + c * 8192;
        for (int t = threadIdx.x; t < 8192; t += 1024) sb[t] = g[t];
        __syncthreads();
        for (int k = 2; k <= 8192; k <<= 1) {
            for (int j = k >> 1; j >= 1; j >>= 1) {
                for (int p = threadIdx.x; p < 4096; p += 1024) {
                    int i  = ((p & ~(j - 1)) << 1) | (p & (j - 1));
                    int gi = (c << 13) | i;
                    bool asc = ((gi & k) == 0);
                    unsigned long long a = sb[i], b2 = sb[i | j];
                    bool sw = asc ? (a > b2) : (a < b2);
                    if (sw) { sb[i] = b2; sb[i | j] = a; }
                }
                __syncthreads();
            }
        }
        for (int t = threadIdx.x; t < 8192; t += 1024) g[t] = sb[t];
        __syncthreads();
    }

    for (int p = threadIdx.x; p < 8192; p += 1024) {
        unsigned long long a = kb[p], b2 = kb[p + 8192];
        if (a > b2) { kb[p] = b2; kb[p + 8192] = a; }
    }
    __syncthreads();

    for (int t = threadIdx.x; t < 8192; t += 1024) sb[t] = kb[t];
    __syncthreads();
    for (int j = 4096; j >= 1; j >>= 1) {
        for (int p = threadIdx.x; p < 4096; p += 1024) {
            int i = ((p & ~(j - 1)) << 1) | (p & (j - 1));
            unsigned long long a = sb[i], b2 = sb[i | j];
            if (a > b2) { sb[i] = b2; sb[i | j] = a; }
        }
        __syncthreads();
    }
    for (int t = threadIdx.x; t < 6016; t += 1024) kb[t] = sb[t];
}

// ---------------- Kernel 3: gather sorted boxes/scores ----------------
__global__ __launch_bounds__(256) void k_gather(
    const unsigned long long* __restrict__ keys, const float4* __restrict__ boxes,
    const float* __restrict__ probs,
    float4* __restrict__ sboxes, float* __restrict__ sscores)
{
    int t = blockIdx.x * 256 + threadIdx.x;
    if (t >= BATCH * PRE) return;
    int b = t / PRE;
    int r = t - b * PRE;
    unsigned long long k = keys[(size_t)b * SORT_N + r];
    int idx = (int)(k & 0xFFFFFFFFu);
    sboxes[(size_t)b * PRE + r]  = boxes[(size_t)b * N_ANC + idx];
    sscores[(size_t)b * PRE + r] = probs[(size_t)b * N_ANC + idx];
}

// ---------------- Kernel 4: IoU bit-matrix + diag tiles ----------------
__global__ __launch_bounds__(256) void k_iou(
    const float4* __restrict__ sboxes, unsigned int* __restrict__ mask,
    unsigned int* __restrict__ diag)
{
    int it = blockIdx.x;   // row tile 0..23
    int jt = blockIdx.y;   // col tile 0..23
    int b  = blockIdx.z;
    if (jt < it) return;   // lower-triangle tiles never consumed by scan

    __shared__ float4 jb[TJ];
    __shared__ float  ja[TJ];
    int t = threadIdx.x;
    int j = jt * TJ + t;
    float4 bj = (j < PRE) ? sboxes[(size_t)b * PRE + j]
                          : make_float4(-2e6f, -2e6f, -1.5e6f, -1.5e6f); // far dummy, area>0
    jb[t] = bj;
    ja[t] = (bj.z - bj.x) * (bj.w - bj.y);
    __syncthreads();

    int i = it * TI + t;
    if (i >= PRE) return;
    float4 bi = sboxes[(size_t)b * PRE + i];
    float areai = (bi.z - bi.x) * (bi.w - bi.y);

    unsigned int w[8];
    if (jt > it) {
        for (int wq = 0; wq < 8; wq++) {
            unsigned int bits = 0u;
            #pragma unroll
            for (int jj = 0; jj < 32; jj++) {
                int lj = wq * 32 + jj;
                float4 bx = jb[lj];
                float ih = fmaxf(fminf(bi.z, bx.z) - fmaxf(bi.x, bx.x), 0.0f);
                float iw = fmaxf(fminf(bi.w, bx.w) - fmaxf(bi.y, bx.y), 0.0f);
                float inter = ih * iw;
                float iou = inter / (areai + ja[lj] - inter + 1e-8f);
                if (iou > 0.7f) bits |= (1u << jj);
            }
            w[wq] = bits;
        }
    } else {
        unsigned int dw = 0u;
        for (int wq = 0; wq < 8; wq++) {
            int jbase = jt * TJ + wq * 32;
            unsigned int bits = 0u;
            if (jbase + 31 > i) {
                #pragma unroll
                for (int jj = 0; jj < 32; jj++) {
                    int lj = wq * 32 + jj;
                    float4 bx = jb[lj];
                    float ih = fmaxf(fminf(bi.z, bx.z) - fmaxf(bi.x, bx.x), 0.0f);
                    float iw = fmaxf(fminf(bi.w, bx.w) - fmaxf(bi.y, bx.y), 0.0f);
                    float inter = ih * iw;
                    float iou = inter / (areai + ja[lj] - inter + 1e-8f);
                    if (iou > 0.7f && (jbase + jj) > i) bits |= (1u << jj);
                }
            }
            w[wq] = bits;
            if (wq == (t >> 5)) dw = bits;   // this row's own-group word
        }
        // diag[g*32+k] = word g of row 32g+k ; contiguous: base + it*256 + t
        diag[(size_t)b * MROWS + it * 256 + t] = dw;
    }

    unsigned int* row = mask + ((size_t)b * MROWS + i) * ROWW + jt * 8;
    ((uint4*)row)[0] = make_uint4(w[0], w[1], w[2], w[3]);
    if (jt < 23) ((uint4*)row)[1] = make_uint4(w[4], w[5], w[6], w[7]);
}

// ---------------- Kernel 5: branchless group-32 scan (1 wave / batch) ----------------
// State distributed: lane l (l<47) owns words 4l..4l+3 (uint4 st).
// Per group: broadcast diag tile (8 uint4), per-lane coalesced row loads
// (32 uint4, predicated on word>=g), register-only serial resolve,
// ballot-based cap/record, unconditional masked OR. No LDS, no branches
// in the OR, all loads pipelined.
__global__ __launch_bounds__(64, 1) void k_scan(
    const unsigned int* __restrict__ mask, const unsigned int* __restrict__ diag,
    int* __restrict__ out_idx, int* __restrict__ out_cnt)
{
    int b = blockIdx.x;
    int lane = threadIdx.x;
    const unsigned int* mb = mask + (size_t)b * MROWS * ROWW;
    const unsigned int* db = diag + (size_t)b * MROWS;
    bool lact = (lane < 47);
    unsigned int lbit  = 1u << (lane & 31);
    unsigned int below = lbit - 1u;

    uint4 st = make_uint4(0, 0, 0, 0);
    int cnt = 0;
    int* oi = out_idx + b * POST;

    for (int g = 0; g < NGRP; g++) {
        // diag tile: wave-uniform address -> scalar-cached broadcast loads
        const uint4* dt = (const uint4*)(db + g * 32);
        uint4 t0 = dt[0], t1 = dt[1], t2 = dt[2], t3 = dt[3];
        uint4 t4 = dt[4], t5 = dt[5], t6 = dt[6], t7 = dt[7];

        // per-lane row words for all 32 rows (coalesced 1 KB per row)
        bool need = lact && (4 * lane + 3 >= g);   // words < g structurally zero
        const unsigned int* gp = mb + (size_t)g * 32 * ROWW + 4 * lane;
        uint4 r[32];
        #pragma unroll
        for (int k = 0; k < 32; k++)
            r[k] = need ? *(const uint4*)(gp + (size_t)k * ROWW)
                        : make_uint4(0, 0, 0, 0);

        // broadcast current state word for this group
        unsigned int cword = (g & 2) ? ((g & 1) ? st.w : st.z)
                                     : ((g & 1) ? st.y : st.x);
        unsigned int swv = __shfl(cword, g >> 2);

        // register tri[] with all-static indices
        unsigned int tri[32];
        tri[0]=t0.x;  tri[1]=t0.y;  tri[2]=t0.z;  tri[3]=t0.w;
        tri[4]=t1.x;  tri[5]=t1.y;  tri[6]=t1.z;  tri[7]=t1.w;
        tri[8]=t2.x;  tri[9]=t2.y;  tri[10]=t2.z; tri[11]=t2.w;
        tri[12]=t3.x; tri[13]=t3.y; tri[14]=t3.z; tri[15]=t3.w;
        tri[16]=t4.x; tri[17]=t4.y; tri[18]=t4.z; tri[19]=t4.w;
        tri[20]=t5.x; tri[21]=t5.y; tri[22]=t5.z; tri[23]=t5.w;
        tri[24]=t6.x; tri[25]=t6.y; tri[26]=t6.z; tri[27]=t6.w;
        tri[28]=t7.x; tri[29]=t7.y; tri[30]=t7.z; tri[31]=t7.w;

        // branchless serial resolve (replicated across lanes)
        unsigned int valid = (g == NGRP - 1) ? 0xFFFFu : 0xFFFFFFFFu;
        unsigned int alive = ~swv & valid;
        unsigned int keepm = 0;
        #pragma unroll
        for (int k = 0; k < 32; k++) {
            unsigned int bit = (alive >> k) & 1u;
            keepm |= bit << k;
            alive &= ~((0u - bit) & tri[k]);
        }

        // parallel cap-truncation + record via ballot (exact reference cap)
        int need_n = POST - cnt;                 // > 0 here
        int rank = __popc(keepm & below);
        bool keep_me = (lane < 32) && (keepm & lbit) && (rank < need_n);
        unsigned long long bal = __ballot(keep_me);
        unsigned int keepm2 = (unsigned int)bal;
        if (keep_me) oi[cnt + rank] = g * 32 + lane;

        // unconditional masked OR of kept rows into distributed state
        #pragma unroll
        for (int k = 0; k < 32; k++) {
            unsigned int m = 0u - ((keepm2 >> k) & 1u);
            st.x |= r[k].x & m; st.y |= r[k].y & m;
            st.z |= r[k].z & m; st.w |= r[k].w & m;
        }

        cnt += __popc(keepm2);
        if (cnt >= POST) break;
    }
    if (lane == 0) out_cnt[b] = cnt;
}

// ---------------- Kernel 6: compact + clip output ----------------
__global__ __launch_bounds__(256) void k_out(
    const float4* __restrict__ sboxes, const float* __restrict__ sscores,
    const int* __restrict__ out_idx, const int* __restrict__ out_cnt,
    float* __restrict__ out)
{
    int t = blockIdx.x * 256 + threadIdx.x;
    if (t >= BATCH * POST) return;
    int b = t / POST;
    int r = t - b * POST;
    float4 v = make_float4(0, 0, 0, 0);
    float sc = 0.f;
    if (r < out_cnt[b]) {
        int i = out_idx[b * POST + r];
        float4 bx = sboxes[(size_t)b * PRE + i];
        v.x = fminf(fmaxf(bx.x, 0.f), 1.f);
        v.y = fminf(fmaxf(bx.y, 0.f), 1.f);
        v.z = fminf(fmaxf(bx.z, 0.f), 1.f);
        v.w = fminf(fmaxf(bx.w, 0.f), 1.f);
        sc = sscores[(size_t)b * PRE + i];
    }
    ((float4*)out)[t] = v;                  // roi_bboxes
    out[(size_t)BATCH * POST * 4 + t] = sc; // roi_scores
}

// ---------------- host ----------------
extern "C" void kernel_launch(void* const* d_in, const int* in_sizes, int n_in,
                              void* d_out, int out_size, void* d_ws, size_t ws_size,
                              hipStream_t stream)
{
    const float* deltas  = (const float*)d_in[0];
    const float* probs   = (const float*)d_in[1];
    const float* anchors = (const float*)d_in[2];
    float* out = (float*)d_out;

    char* ws = (char*)d_ws;
    size_t off = 0;
    auto alloc = [&](size_t bytes) {
        size_t o = off;
        off = (off + bytes + 255) & ~(size_t)255;
        return o;
    };
    float4* boxes            = (float4*)(ws + alloc((size_t)BATCH * N_ANC * 16));
    unsigned long long* keys = (unsigned long long*)(ws + alloc((size_t)BATCH * SORT_N * 8));
    float4* sboxes           = (float4*)(ws + alloc((size_t)BATCH * PRE * 16));
    float* sscores           = (float*)(ws + alloc((size_t)BATCH * PRE * 4));
    unsigned int* mask       = (unsigned int*)(ws + alloc((size_t)BATCH * MROWS * ROWW * 4));
    unsigned int* diag       = (unsigned int*)(ws + alloc((size_t)BATCH * MROWS * 4));
    int* oidx                = (int*)(ws + alloc((size_t)BATCH * POST * 4));
    int* ocnt                = (int*)(ws + alloc((size_t)BATCH * 4));

    k_decode<<<(BATCH * SORT_N + 255) / 256, 256, 0, stream>>>(deltas, probs, anchors, boxes, keys);
    k_sort<<<BATCH, 1024, 0, stream>>>(keys);
    k_gather<<<(BATCH * PRE + 255) / 256, 256, 0, stream>>>(keys, boxes, probs, sboxes, sscores);
    k_iou<<<dim3(24, 24, BATCH), 256, 0, stream>>>(sboxes, mask, diag);
    k_scan<<<BATCH, 64, 0, stream>>>(mask, diag, oidx, ocnt);
    k_out<<<(BATCH * POST + 255) / 256, 256, 0, stream>>>(sboxes, sscores, oidx, ocnt, out);
}